// Round 1
// baseline (210280.591 us; speedup 1.0000x reference)
//
#include <hip/hip_runtime.h>
#include <hip/hip_cooperative_groups.h>
#include <cstddef>

namespace cg = cooperative_groups;

constexpr int kB = 64;    // batch
constexpr int kT = 256;   // time
constexpr int kD = 128;   // input dim
constexpr int kH = 1024;  // hidden
constexpr int kL = 5;     // layers
constexpr int kC = 10;    // classes
constexpr int kG = 4096;  // 4*kH
constexpr int BK = 64;    // K chunk staged in LDS
constexpr int LDA = BK + 4;  // padded LDS row (floats)

__device__ __forceinline__ float sigf(float x) {
  return 1.0f / (1.0f + __expf(-x));
}
__device__ __forceinline__ float tanh_s(float x) {
  float ax = fabsf(x);
  float e = __expf(-2.0f * ax);         // in (0,1], no overflow
  float r = (1.0f - e) / (1.0f + e);
  return copysignf(r, x);
}

// Stage a [64 x BK] chunk of A (rows = batch) into LDS, padded rows.
__device__ __forceinline__ void stage_chunk(float* lds, const float* __restrict__ base,
                                            int rstride, int kb, int tid, bool zero) {
#pragma unroll
  for (int i = 0; i < 4; ++i) {
    int f = tid + 256 * i;      // float4 id, 0..1023
    int b = f >> 4;             // 16 float4 per row
    int kk = (f & 15) << 2;
    float4 v = make_float4(0.f, 0.f, 0.f, 0.f);
    if (!zero) v = *(const float4*)(base + (size_t)b * rstride + kb + kk);
    *(float4*)(lds + (size_t)b * LDA + kk) = v;
  }
}

template <int NC>
__device__ __forceinline__ void gemm_chunk(float (&acc)[4][NC], const float* lds,
                                           const float* __restrict__ wrow, int bi) {
  const float* ar = lds + (size_t)(bi * 4) * LDA;
#pragma unroll 4
  for (int k = 0; k < BK; k += 4) {
    float4 a[4];
#pragma unroll
    for (int j = 0; j < 4; ++j) a[j] = *(const float4*)(ar + (size_t)j * LDA + k);
#pragma unroll
    for (int kk = 0; kk < 4; ++kk) {
      if constexpr (NC == 4) {
        float4 w = *(const float4*)(wrow + (size_t)(k + kk) * kG);
#pragma unroll
        for (int j = 0; j < 4; ++j) {
          float av = ((const float*)&a[j])[kk];
          acc[j][0] = fmaf(av, w.x, acc[j][0]);
          acc[j][1] = fmaf(av, w.y, acc[j][1]);
          acc[j][2] = fmaf(av, w.z, acc[j][2]);
          acc[j][3] = fmaf(av, w.w, acc[j][3]);
        }
      } else {
        float w = wrow[(size_t)(k + kk) * kG];
#pragma unroll
        for (int j = 0; j < 4; ++j) {
          float av = ((const float*)&a[j])[kk];
          acc[j][0] = fmaf(av, w, acc[j][0]);
        }
      }
    }
  }
}

// One LSTM cell tile: CB columns (CB/4 hidden units x 4 gates), all 64 batch rows.
// Thread layout: bi = tid>>4 (4 batch rows each), ci = tid&15 (NC cols each).
template <int CB, int NC>
__device__ __forceinline__ void do_cell(
    int jb, int t, const float* __restrict__ a_base, int a_stride, int Kx,
    const float* __restrict__ Wx, const float* __restrict__ Wh,
    const float* __restrict__ bias, const float* __restrict__ hp_base,
    float* __restrict__ h_out, float* __restrict__ cst, float* lds, int tid) {
  constexpr int UPB = CB / 4;  // units per block
  const int bi = tid >> 4;
  const int ci = tid & 15;
  const int c0 = ci * NC;
  const int wcol = (c0 / UPB) * kH + jb * UPB + (c0 % UPB);

  float acc[4][NC];
#pragma unroll
  for (int j = 0; j < 4; ++j)
#pragma unroll
    for (int m = 0; m < NC; ++m) acc[j][m] = 0.f;

  // part 0: input contribution
  for (int kb = 0; kb < Kx; kb += BK) {
    __syncthreads();
    stage_chunk(lds, a_base, a_stride, kb, tid, false);
    __syncthreads();
    gemm_chunk<NC>(acc, lds, Wx + (size_t)kb * kG + wcol, bi);
  }
  // part 1: recurrent contribution
  for (int kb = 0; kb < kH; kb += BK) {
    __syncthreads();
    stage_chunk(lds, hp_base, kH, kb, tid, hp_base == nullptr);
    __syncthreads();
    gemm_chunk<NC>(acc, lds, Wh + (size_t)kb * kG + wcol, bi);
  }

  // exchange z through LDS so each thread gets the 4 gates of its units
  __syncthreads();
#pragma unroll
  for (int j = 0; j < 4; ++j)
#pragma unroll
    for (int m = 0; m < NC; ++m)
      lds[(size_t)(bi * 4 + j) * LDA + c0 + m] = acc[j][m];
  __syncthreads();

  constexpr int PPT = (64 * UPB) / 256;
#pragma unroll
  for (int i = 0; i < PPT; ++i) {
    int p = tid + 256 * i;
    int b = p / UPB;
    int jj = p % UPB;
    int unit = jb * UPB + jj;
    float zi = lds[(size_t)b * LDA + 0 * UPB + jj] + bias[unit];
    float zf = lds[(size_t)b * LDA + 1 * UPB + jj] + bias[kH + unit];
    float zg = lds[(size_t)b * LDA + 2 * UPB + jj] + bias[2 * kH + unit];
    float zo = lds[(size_t)b * LDA + 3 * UPB + jj] + bias[3 * kH + unit];
    float cp = (t == 0) ? 0.f : cst[(size_t)b * kH + unit];
    float cn = sigf(zf) * cp + sigf(zi) * tanh_s(zg);
    float hn = sigf(zo) * tanh_s(cn);
    cst[(size_t)b * kH + unit] = cn;
    h_out[(size_t)b * kH + unit] = hn;
  }
}

__global__ void __launch_bounds__(256) lstm_wavefront(
    const float* __restrict__ x, const float* __restrict__ Wx0,
    const float* __restrict__ Wxs, const float* __restrict__ Whs,
    const float* __restrict__ bs, const float* __restrict__ W_head,
    const float* __restrict__ b_head, float* __restrict__ out,
    float* __restrict__ h_buf,    // [L][2][B][H]
    float* __restrict__ c_state)  // [L][B][H]
{
  cg::grid_group grid = cg::this_grid();
  __shared__ __align__(16) float lds[64 * LDA];
  const int tid = threadIdx.x;
  const int g = blockIdx.x;       // 0..255
  const int lA = (g >> 6) + 1;    // layers 1..4
  const int jbA = g & 63;         // 64-col tile within layer lA

  for (int s = 0; s < kT + kL - 1; ++s) {
    // --- task A: one 64-col tile of layer lA (K = 1024 + 1024) ---
    {
      int t = s - lA;
      if (t >= 0 && t < kT) {
        const float* a_base =
            h_buf + ((size_t)(lA - 1) * 2 + (t & 1)) * kB * kH;
        const float* hp =
            (t == 0) ? nullptr
                     : h_buf + ((size_t)lA * 2 + ((t - 1) & 1)) * kB * kH;
        float* hout = h_buf + ((size_t)lA * 2 + (t & 1)) * kB * kH;
        do_cell<64, 4>(jbA, t, a_base, kH, kH,
                       Wxs + (size_t)(lA - 1) * kH * kG,
                       Whs + (size_t)lA * kH * kG, bs + (size_t)lA * kG, hp,
                       hout, c_state + (size_t)lA * kB * kH, lds, tid);
      }
    }
    // --- task B: one 16-col tile of layer 0 (K = 128 + 1024) ---
    {
      int t = s;
      if (t < kT) {
        const float* a_base = x + (size_t)t * kD;  // row stride kT*kD
        const float* hp =
            (t == 0) ? nullptr : h_buf + (size_t)(((t - 1) & 1)) * kB * kH;
        float* hout = h_buf + (size_t)(t & 1) * kB * kH;
        do_cell<16, 1>(g, t, a_base, kT * kD, kD, Wx0, Whs, bs, hp, hout,
                       c_state, lds, tid);
      }
    }
    grid.sync();
  }

  // --- head: out[b][c] = h4_last[b] . W_head[:,c] + b_head[c] ---
  if (g < 160) {
    int w = tid >> 6, lane = tid & 63;
    int p = g * 4 + w;  // 0..639
    int b = p / 10, cc = p - b * 10;
    const float* hl =
        h_buf + ((size_t)4 * 2 + ((kT - 1) & 1)) * kB * kH + (size_t)b * kH;
    float sum = 0.f;
    for (int j = lane; j < kH; j += 64) sum += hl[j] * W_head[(size_t)j * kC + cc];
#pragma unroll
    for (int off = 32; off > 0; off >>= 1) sum += __shfl_down(sum, off, 64);
    if (lane == 0) out[p] = sum + b_head[cc];
  }
}

extern "C" void kernel_launch(void* const* d_in, const int* in_sizes, int n_in,
                              void* d_out, int out_size, void* d_ws,
                              size_t ws_size, hipStream_t stream) {
  const float* x = (const float*)d_in[0];
  const float* Wx0 = (const float*)d_in[1];
  const float* Wxs = (const float*)d_in[2];
  const float* Whs = (const float*)d_in[3];
  const float* bs = (const float*)d_in[4];
  const float* W_head = (const float*)d_in[5];
  const float* b_head = (const float*)d_in[6];
  float* out = (float*)d_out;
  float* h_buf = (float*)d_ws;                          // L*2*B*H floats
  float* c_state = h_buf + (size_t)kL * 2 * kB * kH;    // L*B*H floats

  void* args[] = {&x, &Wx0, &Wxs, &Whs, &bs, &W_head, &b_head,
                  &out, &h_buf, &c_state};
  hipLaunchCooperativeKernel((void*)lstm_wavefront, dim3(256), dim3(256), args,
                             0, stream);
}

// Round 2
// 30106.873 us; speedup vs baseline: 6.9845x; 6.9845x over previous
//
#include <hip/hip_runtime.h>
#include <hip/hip_cooperative_groups.h>
#include <hip/hip_bf16.h>
#include <cstddef>

namespace cg = cooperative_groups;

typedef unsigned short u16;
typedef __attribute__((ext_vector_type(8))) short s8;   // 8 bf16 = 4 VGPRs
typedef __attribute__((ext_vector_type(4))) float f4;   // MFMA acc

constexpr int kB = 64, kT = 256, kD = 128, kH = 1024, kL = 5, kC = 10, kG = 4096;

__device__ __forceinline__ float sigf(float x) { return 1.f / (1.f + __expf(-x)); }
__device__ __forceinline__ float tanh_s(float x) {
  float ax = fabsf(x);
  float e = __expf(-2.f * ax);
  float r = (1.f - e) / (1.f + e);
  return copysignf(r, x);
}
__device__ __forceinline__ void split_bf16(float v, short& hi, short& lo) {
  __hip_bfloat16 h = __float2bfloat16(v);
  hi = __builtin_bit_cast(short, h);
  float fh = __bfloat162float(h);
  __hip_bfloat16 l = __float2bfloat16(v - fh);
  lo = __builtin_bit_cast(short, l);
}
__device__ __forceinline__ float bf2f(u16 v) {
  unsigned u = ((unsigned)v) << 16;
  return __builtin_bit_cast(float, u);
}

// Stage 4 chunks (32 KB) into LDS in MFMA-A fragment order.
// Chunk c covers k = [k00 + c*32, +32) of a [64 x K] bf16 activation matrix
// stored row-major [b][kH]. hi source bh, lo source bl. zero => write zeros.
__device__ __forceinline__ void stage4(unsigned char* st, const u16* __restrict__ bh,
                                       const u16* __restrict__ bl, int k00, bool zero,
                                       int tid) {
#pragma unroll
  for (int j = 0; j < 4; ++j) {
    int s = tid + 512 * j;          // 16B slot id, 0..2047
    int c = s >> 9;                 // chunk 0..3
    int half = (s >> 8) & 1;        // 0 = hi, 1 = lo
    int n = s & 255;                // frag slot within 4KB half
    int b = ((n >> 6) << 4) | (n & 15);
    int koff = k00 + c * 32 + ((n >> 4) & 3) * 8;
    uint4 v = make_uint4(0, 0, 0, 0);
    if (!zero) {
      const u16* src = half ? bl : bh;
      v = *(const uint4*)(src + (size_t)b * kH + koff);
    }
    *(uint4*)(st + (s << 4)) = v;
  }
}

__global__ void __launch_bounds__(512, 2) lstm_persist(
    const float* __restrict__ x, const float* __restrict__ Wx0,
    const float* __restrict__ Wxs, const float* __restrict__ Whs,
    const float* __restrict__ bs, const float* __restrict__ W_head,
    const float* __restrict__ b_head, float* __restrict__ out,
    u16* __restrict__ hhi, u16* __restrict__ hlo) {
  cg::grid_group grid = cg::this_grid();
  __shared__ __align__(16) unsigned char stage[32768];  // 4 chunk slots x 8KB
  __shared__ float zA[64 * 66];
  __shared__ float zB[64 * 18];

  const int tid = threadIdx.x;
  const int wv = tid >> 6, lane = tid & 63, quad = lane >> 4, r = lane & 15;
  const int ch = wv >> 2, kq = wv & 3;  // task-A wave role
  const int g = blockIdx.x;
  const int lA = (g >> 6) + 1;  // task-A layer 1..4
  const int jb = g & 63;        // task-A 16-unit tile
  const int ub = g * 4;         // task-B unit base (4 units of layer 0)

  // ---- one-time: load weights into register fragments (bf16 hi/lo split) ----
  const float* __restrict__ WxA = Wxs + (size_t)(lA - 1) * kH * kG;
  const float* __restrict__ WhA = Whs + (size_t)lA * kH * kG;

  s8 wA[16][2][2];  // [chunk idx][ntile-local][hi/lo]
#pragma unroll
  for (int i = 0; i < 16; ++i) {
    int kc = 4 * i + kq;
    const float* W = (kc < 32) ? WxA : WhA;
    int krow0 = (kc < 32) ? kc * 32 : (kc - 32) * 32;
#pragma unroll
    for (int ntl = 0; ntl < 2; ++ntl) {
      int col = (2 * ch + ntl) * kH + jb * 16 + r;
      s8 h8, l8;
#pragma unroll
      for (int j = 0; j < 8; ++j) {
        float w = W[(size_t)(krow0 + quad * 8 + j) * kG + col];
        short hh, ll;
        split_bf16(w, hh, ll);
        h8[j] = hh;
        l8[j] = ll;
      }
      wA[i][ntl][0] = h8;
      wA[i][ntl][1] = l8;
    }
  }
  s8 wBh[4][2], wBx[2];
  {
    int colB = (r >> 2) * kH + ub + (r & 3);
#pragma unroll
    for (int j2 = 0; j2 < 4; ++j2) {
      int kb = (wv & 3) + 4 * (2 * j2 + (wv >> 2));
      int krow0 = kb * 32;
      s8 h8, l8;
#pragma unroll
      for (int j = 0; j < 8; ++j) {
        float w = Whs[(size_t)(krow0 + quad * 8 + j) * kG + colB];
        short hh, ll;
        split_bf16(w, hh, ll);
        h8[j] = hh;
        l8[j] = ll;
      }
      wBh[j2][0] = h8;
      wBh[j2][1] = l8;
    }
    int xc = wv & 3;  // used by waves 4..7
    s8 h8, l8;
#pragma unroll
    for (int j = 0; j < 8; ++j) {
      float w = Wx0[(size_t)(xc * 32 + quad * 8 + j) * kG + colB];
      short hh, ll;
      split_bf16(w, hh, ll);
      h8[j] = hh;
      l8[j] = ll;
    }
    wBx[0] = h8;
    wBx[1] = l8;
  }

  // biases + persistent cell state (registers)
  float bA[4], bB[4];
  {
    int u = tid & 15;
#pragma unroll
    for (int g4 = 0; g4 < 4; ++g4) bA[g4] = bs[(size_t)lA * kG + g4 * kH + jb * 16 + u];
    int u2 = tid & 3;
#pragma unroll
    for (int g4 = 0; g4 < 4; ++g4) bB[g4] = bs[(size_t)g4 * kH + ub + u2];
  }
  float cA0 = 0.f, cA1 = 0.f, cB0 = 0.f;
  const f4 zero4 = {0.f, 0.f, 0.f, 0.f};

  // ---- wavefront loop ----
  for (int s = 0; s < kT + kL - 1; ++s) {
    for (int i = tid; i < 64 * 66; i += 512) zA[i] = 0.f;
    for (int i = tid; i < 64 * 18; i += 512) zB[i] = 0.f;
    __syncthreads();

    const int tA = s - lA;
    const int tB = s;

    if (tA >= 0 && tA < kT) {
      const int par = tA & 1, rpar = (tA - 1) & 1;
      const u16* IH = hhi + (size_t)((lA - 1) * 2 + par) * kB * kH;
      const u16* IL = hlo + (size_t)((lA - 1) * 2 + par) * kB * kH;
      const u16* RH = hhi + (size_t)(lA * 2 + rpar) * kB * kH;
      const u16* RL = hlo + (size_t)(lA * 2 + rpar) * kB * kH;
      f4 accA[2][4];
#pragma unroll
      for (int a = 0; a < 2; ++a)
#pragma unroll
        for (int b = 0; b < 4; ++b) accA[a][b] = zero4;

#pragma unroll
      for (int p = 0; p < 16; ++p) {
        __syncthreads();
        const bool inpart = (p < 8);
        stage4(stage, inpart ? IH : RH, inpart ? IL : RL,
               inpart ? p * 128 : (p - 8) * 128, (!inpart) && (tA == 0), tid);
        __syncthreads();
        const unsigned char* slot = stage + (kq << 13);
#pragma unroll
        for (int mt = 0; mt < 4; ++mt) {
          s8 ah = *(const s8*)(slot + ((mt * 64 + lane) << 4));
          s8 al = *(const s8*)(slot + 4096 + ((mt * 64 + lane) << 4));
#pragma unroll
          for (int ntl = 0; ntl < 2; ++ntl) {
            f4 a = accA[ntl][mt];
            a = __builtin_amdgcn_mfma_f32_16x16x32_bf16(ah, wA[p][ntl][0], a, 0, 0, 0);
            a = __builtin_amdgcn_mfma_f32_16x16x32_bf16(al, wA[p][ntl][0], a, 0, 0, 0);
            a = __builtin_amdgcn_mfma_f32_16x16x32_bf16(ah, wA[p][ntl][1], a, 0, 0, 0);
            accA[ntl][mt] = a;
          }
        }
      }
#pragma unroll
      for (int ntl = 0; ntl < 2; ++ntl)
#pragma unroll
        for (int mt = 0; mt < 4; ++mt)
#pragma unroll
          for (int v = 0; v < 4; ++v) {
            int brow = mt * 16 + quad * 4 + v;
            atomicAdd(&zA[brow * 66 + (2 * ch + ntl) * 16 + r], accA[ntl][mt][v]);
          }
    }

    if (tB < kT) {
      const int rpar = (tB - 1) & 1;
      const u16* H0H = hhi + (size_t)rpar * kB * kH;
      const u16* H0L = hlo + (size_t)rpar * kB * kH;
      f4 accB[4];
#pragma unroll
      for (int b = 0; b < 4; ++b) accB[b] = zero4;

#pragma unroll
      for (int q = 0; q < 8; ++q) {
        __syncthreads();
        stage4(stage, H0H, H0L, q * 128, (tB == 0), tid);
        __syncthreads();
        if ((wv >> 2) == (q & 1)) {
          const unsigned char* slot = stage + ((wv & 3) << 13);
          const int j2 = q >> 1;
#pragma unroll
          for (int mt = 0; mt < 4; ++mt) {
            s8 ah = *(const s8*)(slot + ((mt * 64 + lane) << 4));
            s8 al = *(const s8*)(slot + 4096 + ((mt * 64 + lane) << 4));
            f4 a = accB[mt];
            a = __builtin_amdgcn_mfma_f32_16x16x32_bf16(ah, wBh[j2][0], a, 0, 0, 0);
            a = __builtin_amdgcn_mfma_f32_16x16x32_bf16(al, wBh[j2][0], a, 0, 0, 0);
            a = __builtin_amdgcn_mfma_f32_16x16x32_bf16(ah, wBh[j2][1], a, 0, 0, 0);
            accB[mt] = a;
          }
        }
      }
      // x chunks: convert fp32 -> hi/lo and stage
      __syncthreads();
#pragma unroll
      for (int j = 0; j < 2; ++j) {
        int s2 = tid + 512 * j;
        int c = s2 >> 8, n = s2 & 255;
        int b = ((n >> 6) << 4) | (n & 15);
        int kg = (n >> 4) & 3;
        const float* sx = x + (size_t)b * kT * kD + (size_t)tB * kD + c * 32 + kg * 8;
        float4 v0 = *(const float4*)sx;
        float4 v1 = *(const float4*)(sx + 4);
        float vv[8] = {v0.x, v0.y, v0.z, v0.w, v1.x, v1.y, v1.z, v1.w};
        s8 h8, l8;
#pragma unroll
        for (int e = 0; e < 8; ++e) {
          short hh, ll;
          split_bf16(vv[e], hh, ll);
          h8[e] = hh;
          l8[e] = ll;
        }
        *(s8*)(stage + c * 8192 + n * 16) = h8;
        *(s8*)(stage + c * 8192 + 4096 + n * 16) = l8;
      }
      __syncthreads();
      if (wv >= 4) {
        const unsigned char* slot = stage + ((wv - 4) << 13);
#pragma unroll
        for (int mt = 0; mt < 4; ++mt) {
          s8 ah = *(const s8*)(slot + ((mt * 64 + lane) << 4));
          s8 al = *(const s8*)(slot + 4096 + ((mt * 64 + lane) << 4));
          f4 a = accB[mt];
          a = __builtin_amdgcn_mfma_f32_16x16x32_bf16(ah, wBx[0], a, 0, 0, 0);
          a = __builtin_amdgcn_mfma_f32_16x16x32_bf16(al, wBx[0], a, 0, 0, 0);
          a = __builtin_amdgcn_mfma_f32_16x16x32_bf16(ah, wBx[1], a, 0, 0, 0);
          accB[mt] = a;
        }
      }
#pragma unroll
      for (int mt = 0; mt < 4; ++mt)
#pragma unroll
        for (int v = 0; v < 4; ++v)
          atomicAdd(&zB[(mt * 16 + quad * 4 + v) * 18 + r], accB[mt][v]);
    }

    __syncthreads();

    // ---- gate math + h store (hi/lo bf16) ----
    if (tA >= 0 && tA < kT) {
      const int par = tA & 1;
      u16* HH = hhi + (size_t)(lA * 2 + par) * kB * kH;
      u16* HL = hlo + (size_t)(lA * 2 + par) * kB * kH;
#pragma unroll
      for (int rp = 0; rp < 2; ++rp) {
        int p2 = tid + 512 * rp;
        int b = p2 >> 4, u = p2 & 15;
        float zi = zA[b * 66 + u] + bA[0];
        float zf = zA[b * 66 + 16 + u] + bA[1];
        float zg = zA[b * 66 + 32 + u] + bA[2];
        float zo = zA[b * 66 + 48 + u] + bA[3];
        float cp = (tA == 0) ? 0.f : (rp ? cA1 : cA0);
        float cn = sigf(zf) * cp + sigf(zi) * tanh_s(zg);
        float hn = sigf(zo) * tanh_s(cn);
        if (rp) cA1 = cn; else cA0 = cn;
        short hh, ll;
        split_bf16(hn, hh, ll);
        size_t off = (size_t)b * kH + jb * 16 + u;
        HH[off] = (u16)hh;
        HL[off] = (u16)ll;
      }
    }
    if (tB < kT && tid < 256) {
      const int par = tB & 1;
      u16* HH = hhi + (size_t)par * kB * kH;
      u16* HL = hlo + (size_t)par * kB * kH;
      int b = tid >> 2, u = tid & 3;
      float zi = zB[b * 18 + u] + bB[0];
      float zf = zB[b * 18 + 4 + u] + bB[1];
      float zg = zB[b * 18 + 8 + u] + bB[2];
      float zo = zB[b * 18 + 12 + u] + bB[3];
      float cp = (tB == 0) ? 0.f : cB0;
      float cn = sigf(zf) * cp + sigf(zi) * tanh_s(zg);
      float hn = sigf(zo) * tanh_s(cn);
      cB0 = cn;
      short hh, ll;
      split_bf16(hn, hh, ll);
      size_t off = (size_t)b * kH + ub + u;
      HH[off] = (u16)hh;
      HL[off] = (u16)ll;
    }
    grid.sync();
  }

  // ---- head: out[b][c] from h^4 at t=255 (parity 1) ----
  if (g < 80) {
    int p = g * 8 + wv;  // 0..639
    int b = p / 10, cc = p - b * 10;
    const u16* HH = hhi + (size_t)(4 * 2 + 1) * kB * kH + (size_t)b * kH;
    const u16* HL = hlo + (size_t)(4 * 2 + 1) * kB * kH + (size_t)b * kH;
    float sum = 0.f;
    for (int j = lane; j < kH; j += 64)
      sum += (bf2f(HH[j]) + bf2f(HL[j])) * W_head[(size_t)j * kC + cc];
#pragma unroll
    for (int off = 32; off > 0; off >>= 1) sum += __shfl_down(sum, off, 64);
    if (lane == 0) out[p] = sum + b_head[cc];
  }
}

extern "C" void kernel_launch(void* const* d_in, const int* in_sizes, int n_in,
                              void* d_out, int out_size, void* d_ws, size_t ws_size,
                              hipStream_t stream) {
  const float* x = (const float*)d_in[0];
  const float* Wx0 = (const float*)d_in[1];
  const float* Wxs = (const float*)d_in[2];
  const float* Whs = (const float*)d_in[3];
  const float* bs = (const float*)d_in[4];
  const float* W_head = (const float*)d_in[5];
  const float* b_head = (const float*)d_in[6];
  float* out = (float*)d_out;
  u16* hhi = (u16*)d_ws;                          // [5][2][64][1024] bf16-hi
  u16* hlo = hhi + (size_t)kL * 2 * kB * kH;      // same shape, lo part

  void* args[] = {&x, &Wx0, &Wxs, &Whs, &bs, &W_head, &b_head, &out, &hhi, &hlo};
  hipLaunchCooperativeKernel((void*)lstm_persist, dim3(256), dim3(512), args, 0,
                             stream);
}

// Round 3
// 27928.122 us; speedup vs baseline: 7.5293x; 1.0780x over previous
//
#include <hip/hip_runtime.h>
#include <hip/hip_cooperative_groups.h>
#include <hip/hip_bf16.h>
#include <cstddef>

namespace cg = cooperative_groups;

typedef unsigned short u16;
typedef __attribute__((ext_vector_type(8))) short s8;   // 8 bf16 = 4 VGPRs
typedef __attribute__((ext_vector_type(4))) float f4;   // MFMA acc

constexpr int kB = 64, kT = 256, kD = 128, kH = 1024, kL = 5, kC = 10, kG = 4096;
constexpr int BH = kB * kH;
constexpr size_t WLA_ELEMS = (size_t)256 * 8 * 2048 * 8;  // 33.5M u16 (67 MB)
constexpr size_t WLB_ELEMS = (size_t)256 * 8 * 5 * 64 * 8; // 5.2M u16 (10.5 MB)
constexpr size_t H_ELEMS = (size_t)kL * 2 * BH;            // per hi or lo buffer

__device__ __forceinline__ float sigf(float x) { return 1.f / (1.f + __expf(-x)); }
__device__ __forceinline__ float tanh_s(float x) {
  float ax = fabsf(x);
  float e = __expf(-2.f * ax);
  float r = (1.f - e) / (1.f + e);
  return copysignf(r, x);
}
__device__ __forceinline__ void split_bf16(float v, short& hi, short& lo) {
  __hip_bfloat16 h = __float2bfloat16(v);
  hi = __builtin_bit_cast(short, h);
  float fh = __bfloat162float(h);
  __hip_bfloat16 l = __float2bfloat16(v - fh);
  lo = __builtin_bit_cast(short, l);
}
__device__ __forceinline__ short hi_bf16(float v) {
  __hip_bfloat16 h = __float2bfloat16(v);
  return __builtin_bit_cast(short, h);
}
__device__ __forceinline__ float bf2f(u16 v) {
  unsigned u = ((unsigned)v) << 16;
  return __builtin_bit_cast(float, u);
}

// ---- prep: split weights, write LO parts in per-(block,wave) fragment order ----
__global__ void __launch_bounds__(512) split_wl(const float* __restrict__ Wx0,
                                                const float* __restrict__ Wxs,
                                                const float* __restrict__ Whs,
                                                u16* __restrict__ wlA,
                                                u16* __restrict__ wlB) {
  const int g = blockIdx.x, tid = threadIdx.x;
  const int wv = tid >> 6, lane = tid & 63, quad = lane >> 4, r = lane & 15;
  const int lA = (g >> 6) + 1, jb = g & 63, kq = wv & 3, ch = wv >> 2;
  const float* WxA = Wxs + (size_t)(lA - 1) * kH * kG;
  const float* WhA = Whs + (size_t)lA * kH * kG;

  u16* dA = wlA + (size_t)(g * 8 + wv) * 16384;
  for (int p = 0; p < 16; ++p) {
    int kc = 4 * p + kq;
    const float* W = (kc < 32) ? WxA : WhA;
    int krow0 = (kc & 31) * 32 + quad * 8;
    for (int ntl = 0; ntl < 2; ++ntl) {
      int col = (2 * ch + ntl) * kH + jb * 16 + r;
      s8 l8;
      for (int j = 0; j < 8; ++j) {
        float w = W[(size_t)(krow0 + j) * kG + col];
        short hh, ll;
        split_bf16(w, hh, ll);
        l8[j] = ll;
      }
      *(s8*)(dA + (size_t)((p * 2 + ntl) * 64 + lane) * 8) = l8;
    }
  }

  u16* dB = wlB + (size_t)(g * 8 + wv) * 2560;
  int colB = (r >> 2) * kH + g * 4 + (r & 3);
  for (int j2 = 0; j2 < 4; ++j2) {
    int kb = (wv & 3) + 4 * (2 * j2 + (wv >> 2));
    int krow0 = kb * 32 + quad * 8;
    s8 l8;
    for (int j = 0; j < 8; ++j) {
      float w = Whs[(size_t)(krow0 + j) * kG + colB];
      short hh, ll;
      split_bf16(w, hh, ll);
      l8[j] = ll;
    }
    *(s8*)(dB + (size_t)(j2 * 64 + lane) * 8) = l8;
  }
  {
    int krow0 = (wv & 3) * 32 + quad * 8;
    s8 l8;
    for (int j = 0; j < 8; ++j) {
      float w = Wx0[(size_t)(krow0 + j) * kG + colB];
      short hh, ll;
      split_bf16(w, hh, ll);
      l8[j] = ll;
    }
    *(s8*)(dB + (size_t)(4 * 64 + lane) * 8) = l8;
  }
}

// ---- main persistent kernel ----
__global__ void __launch_bounds__(512, 2) lstm_persist(
    const float* __restrict__ x, const float* __restrict__ Wx0,
    const float* __restrict__ Wxs, const float* __restrict__ Whs,
    const float* __restrict__ bs, const float* __restrict__ W_head,
    const float* __restrict__ b_head, float* __restrict__ out,
    u16* __restrict__ hhi, u16* __restrict__ hlo,
    const u16* __restrict__ wlA, const u16* __restrict__ wlB) {
  cg::grid_group grid = cg::this_grid();
  __shared__ float zA[64 * 66];
  __shared__ float zB[64 * 18];
  __shared__ __align__(16) unsigned char xstage[32768];

  const int tid = threadIdx.x;
  const int wv = tid >> 6, lane = tid & 63, quad = lane >> 4, r = lane & 15;
  const int ch = wv >> 2, kq = wv & 3;
  const int g = blockIdx.x;
  const int lA = (g >> 6) + 1;
  const int jb = g & 63;
  const int ub = g * 4;

  // ---- one-time preload: HI weight fragments into registers ----
  const float* __restrict__ WxA = Wxs + (size_t)(lA - 1) * kH * kG;
  const float* __restrict__ WhA = Whs + (size_t)lA * kH * kG;

  s8 wA[16][2];  // 128 VGPRs
#pragma unroll
  for (int p = 0; p < 16; ++p) {
    int kc = 4 * p + kq;
    const float* W = (kc < 32) ? WxA : WhA;
    int krow0 = (kc & 31) * 32 + quad * 8;
#pragma unroll
    for (int ntl = 0; ntl < 2; ++ntl) {
      int col = (2 * ch + ntl) * kH + jb * 16 + r;
      s8 h8;
#pragma unroll
      for (int j = 0; j < 8; ++j) h8[j] = hi_bf16(W[(size_t)(krow0 + j) * kG + col]);
      wA[p][ntl] = h8;
    }
  }
  s8 wBh[4], wBx;
  {
    int colB = (r >> 2) * kH + ub + (r & 3);
#pragma unroll
    for (int j2 = 0; j2 < 4; ++j2) {
      int kb = (wv & 3) + 4 * (2 * j2 + (wv >> 2));
      int krow0 = kb * 32 + quad * 8;
      s8 h8;
#pragma unroll
      for (int j = 0; j < 8; ++j) h8[j] = hi_bf16(Whs[(size_t)(krow0 + j) * kG + colB]);
      wBh[j2] = h8;
    }
    int krow0 = (wv & 3) * 32 + quad * 8;
    s8 h8;
#pragma unroll
    for (int j = 0; j < 8; ++j) h8[j] = hi_bf16(Wx0[(size_t)(krow0 + j) * kG + colB]);
    wBx = h8;
  }

  float bA[4], bB[4];
  {
    int u = tid & 15;
#pragma unroll
    for (int g4 = 0; g4 < 4; ++g4) bA[g4] = bs[(size_t)lA * kG + g4 * kH + jb * 16 + u];
    int u2 = tid & 3;
#pragma unroll
    for (int g4 = 0; g4 < 4; ++g4) bB[g4] = bs[(size_t)g4 * kH + ub + u2];
  }
  float cA0 = 0.f, cA1 = 0.f, cB0 = 0.f;
  const s8 zf = {0, 0, 0, 0, 0, 0, 0, 0};
  const f4 zero4 = {0.f, 0.f, 0.f, 0.f};

  const u16* wlAs = wlA + (size_t)(g * 8 + wv) * 16384;
  const u16* wlBs = wlB + (size_t)(g * 8 + wv) * 2560;

  // ---- wavefront loop: 2 syncthreads + 1 grid.sync per step ----
  for (int s = 0; s < kT + kL - 1; ++s) {
    const int tA = s - lA;
    const int tB = s;

    for (int i = tid; i < 64 * 66; i += 512) zA[i] = 0.f;
    for (int i = tid; i < 64 * 18; i += 512) zB[i] = 0.f;
    if (tB < kT) {
      // stage x[:, tB, :] as hi/lo fragments into LDS
#pragma unroll
      for (int j = 0; j < 2; ++j) {
        int s2 = tid + 512 * j;
        int c = s2 >> 8, n = s2 & 255;
        int b = ((n >> 6) << 4) | (n & 15);
        int kg = (n >> 4) & 3;
        const float* sx = x + (size_t)b * kT * kD + (size_t)tB * kD + c * 32 + kg * 8;
        float4 v0 = *(const float4*)sx;
        float4 v1 = *(const float4*)(sx + 4);
        float vv[8] = {v0.x, v0.y, v0.z, v0.w, v1.x, v1.y, v1.z, v1.w};
        s8 h8, l8;
#pragma unroll
        for (int e = 0; e < 8; ++e) {
          short hh, ll;
          split_bf16(vv[e], hh, ll);
          h8[e] = hh;
          l8[e] = ll;
        }
        *(s8*)(xstage + c * 8192 + n * 16) = h8;
        *(s8*)(xstage + c * 8192 + 4096 + n * 16) = l8;
      }
    }
    __syncthreads();

    // ---- task A: 64 cols of layer lA ----
    if (tA >= 0 && tA < kT) {
      const u16* IH = hhi + (size_t)((lA - 1) * 2 + (tA & 1)) * BH;
      const u16* IL = hlo + (size_t)((lA - 1) * 2 + (tA & 1)) * BH;
      const u16* RH = hhi + (size_t)(lA * 2 + ((tA - 1) & 1)) * BH;
      const u16* RL = hlo + (size_t)(lA * 2 + ((tA - 1) & 1)) * BH;
      f4 accA[2][4];
#pragma unroll
      for (int a = 0; a < 2; ++a)
#pragma unroll
        for (int b = 0; b < 4; ++b) accA[a][b] = zero4;

#pragma unroll
      for (int p = 0; p < 16; ++p) {
        const bool inpart = (p < 8);
        const u16* SH = inpart ? IH : RH;
        const u16* SL = inpart ? IL : RL;
        const bool zz = (!inpart) && (tA == 0);
        const int k0 = (p & 7) * 128 + kq * 32 + quad * 8;
        s8 ah[4], al[4];
#pragma unroll
        for (int mt = 0; mt < 4; ++mt) {
          int off = (mt * 16 + r) * kH + k0;
          if (zz) {
            ah[mt] = zf;
            al[mt] = zf;
          } else {
            ah[mt] = *(const s8*)(SH + off);
            al[mt] = *(const s8*)(SL + off);
          }
        }
        s8 w0 = *(const s8*)(wlAs + (size_t)((p * 2 + 0) * 64 + lane) * 8);
        s8 w1 = *(const s8*)(wlAs + (size_t)((p * 2 + 1) * 64 + lane) * 8);
#pragma unroll
        for (int mt = 0; mt < 4; ++mt) {
          f4 a0 = accA[0][mt], a1 = accA[1][mt];
          a0 = __builtin_amdgcn_mfma_f32_16x16x32_bf16(ah[mt], wA[p][0], a0, 0, 0, 0);
          a0 = __builtin_amdgcn_mfma_f32_16x16x32_bf16(al[mt], wA[p][0], a0, 0, 0, 0);
          a0 = __builtin_amdgcn_mfma_f32_16x16x32_bf16(ah[mt], w0, a0, 0, 0, 0);
          a1 = __builtin_amdgcn_mfma_f32_16x16x32_bf16(ah[mt], wA[p][1], a1, 0, 0, 0);
          a1 = __builtin_amdgcn_mfma_f32_16x16x32_bf16(al[mt], wA[p][1], a1, 0, 0, 0);
          a1 = __builtin_amdgcn_mfma_f32_16x16x32_bf16(ah[mt], w1, a1, 0, 0, 0);
          accA[0][mt] = a0;
          accA[1][mt] = a1;
        }
      }
#pragma unroll
      for (int ntl = 0; ntl < 2; ++ntl)
#pragma unroll
        for (int mt = 0; mt < 4; ++mt)
#pragma unroll
          for (int v = 0; v < 4; ++v)
            atomicAdd(&zA[(mt * 16 + quad * 4 + v) * 66 + (2 * ch + ntl) * 16 + r],
                      accA[ntl][mt][v]);
    }

    // ---- task B: 4 units of layer 0 ----
    if (tB < kT) {
      const u16* H0H = hhi + (size_t)((tB - 1) & 1) * BH;
      const u16* H0L = hlo + (size_t)((tB - 1) & 1) * BH;
      const bool z0 = (tB == 0);
      f4 accB[4];
#pragma unroll
      for (int b = 0; b < 4; ++b) accB[b] = zero4;

#pragma unroll
      for (int j2 = 0; j2 < 4; ++j2) {
        int kb = (wv & 3) + 4 * (2 * j2 + (wv >> 2));
        int k0 = kb * 32 + quad * 8;
        s8 wlv = *(const s8*)(wlBs + (size_t)(j2 * 64 + lane) * 8);
#pragma unroll
        for (int mt = 0; mt < 4; ++mt) {
          int off = (mt * 16 + r) * kH + k0;
          s8 ah = z0 ? zf : *(const s8*)(H0H + off);
          s8 al = z0 ? zf : *(const s8*)(H0L + off);
          f4 a = accB[mt];
          a = __builtin_amdgcn_mfma_f32_16x16x32_bf16(ah, wBh[j2], a, 0, 0, 0);
          a = __builtin_amdgcn_mfma_f32_16x16x32_bf16(al, wBh[j2], a, 0, 0, 0);
          a = __builtin_amdgcn_mfma_f32_16x16x32_bf16(ah, wlv, a, 0, 0, 0);
          accB[mt] = a;
        }
      }
      if (wv >= 4) {
        const int c = wv - 4;
        s8 wlx = *(const s8*)(wlBs + (size_t)(4 * 64 + lane) * 8);
#pragma unroll
        for (int mt = 0; mt < 4; ++mt) {
          s8 ah = *(const s8*)(xstage + c * 8192 + (mt * 64 + lane) * 16);
          s8 al = *(const s8*)(xstage + c * 8192 + 4096 + (mt * 64 + lane) * 16);
          f4 a = accB[mt];
          a = __builtin_amdgcn_mfma_f32_16x16x32_bf16(ah, wBx, a, 0, 0, 0);
          a = __builtin_amdgcn_mfma_f32_16x16x32_bf16(al, wBx, a, 0, 0, 0);
          a = __builtin_amdgcn_mfma_f32_16x16x32_bf16(ah, wlx, a, 0, 0, 0);
          accB[mt] = a;
        }
      }
#pragma unroll
      for (int mt = 0; mt < 4; ++mt)
#pragma unroll
        for (int v = 0; v < 4; ++v)
          atomicAdd(&zB[(mt * 16 + quad * 4 + v) * 18 + r], accB[mt][v]);
    }

    __syncthreads();

    // ---- gates + h store ----
    if (tA >= 0 && tA < kT) {
      const int par = tA & 1;
      u16* HH = hhi + (size_t)(lA * 2 + par) * BH;
      u16* HL = hlo + (size_t)(lA * 2 + par) * BH;
#pragma unroll
      for (int rp = 0; rp < 2; ++rp) {
        int p2 = tid + 512 * rp;
        int b = p2 >> 4, u = p2 & 15;
        float zi = zA[b * 66 + u] + bA[0];
        float zfg = zA[b * 66 + 16 + u] + bA[1];
        float zg = zA[b * 66 + 32 + u] + bA[2];
        float zo = zA[b * 66 + 48 + u] + bA[3];
        float cp = (tA == 0) ? 0.f : (rp ? cA1 : cA0);
        float cn = sigf(zfg) * cp + sigf(zi) * tanh_s(zg);
        float hn = sigf(zo) * tanh_s(cn);
        if (rp) cA1 = cn; else cA0 = cn;
        short hh, ll;
        split_bf16(hn, hh, ll);
        size_t off = (size_t)b * kH + jb * 16 + u;
        HH[off] = (u16)hh;
        HL[off] = (u16)ll;
      }
    }
    if (tB < kT && tid < 256) {
      const int par = tB & 1;
      u16* HH = hhi + (size_t)par * BH;
      u16* HL = hlo + (size_t)par * BH;
      int b = tid >> 2, u = tid & 3;
      float zi = zB[b * 18 + u] + bB[0];
      float zfg = zB[b * 18 + 4 + u] + bB[1];
      float zg = zB[b * 18 + 8 + u] + bB[2];
      float zo = zB[b * 18 + 12 + u] + bB[3];
      float cp = (tB == 0) ? 0.f : cB0;
      float cn = sigf(zfg) * cp + sigf(zi) * tanh_s(zg);
      float hn = sigf(zo) * tanh_s(cn);
      cB0 = cn;
      short hh, ll;
      split_bf16(hn, hh, ll);
      size_t off = (size_t)b * kH + ub + u;
      HH[off] = (u16)hh;
      HL[off] = (u16)ll;
    }
    grid.sync();
  }

  // ---- head ----
  if (g < 80) {
    int p = g * 8 + wv;
    int b = p / 10, cc = p - b * 10;
    const u16* HH = hhi + (size_t)(4 * 2 + 1) * BH + (size_t)b * kH;
    const u16* HL = hlo + (size_t)(4 * 2 + 1) * BH + (size_t)b * kH;
    float sum = 0.f;
    for (int j = lane; j < kH; j += 64)
      sum += (bf2f(HH[j]) + bf2f(HL[j])) * W_head[(size_t)j * kC + cc];
#pragma unroll
    for (int off = 32; off > 0; off >>= 1) sum += __shfl_down(sum, off, 64);
    if (lane == 0) out[p] = sum + b_head[cc];
  }
}

// Fallback weight-lo buffer, allocated at library load (NOT inside kernel_launch).
static u16* g_wl = nullptr;
__attribute__((constructor)) static void alloc_wl() {
  hipMalloc((void**)&g_wl, (WLA_ELEMS + WLB_ELEMS) * sizeof(u16));
}

extern "C" void kernel_launch(void* const* d_in, const int* in_sizes, int n_in,
                              void* d_out, int out_size, void* d_ws, size_t ws_size,
                              hipStream_t stream) {
  const float* x = (const float*)d_in[0];
  const float* Wx0 = (const float*)d_in[1];
  const float* Wxs = (const float*)d_in[2];
  const float* Whs = (const float*)d_in[3];
  const float* bs = (const float*)d_in[4];
  const float* W_head = (const float*)d_in[5];
  const float* b_head = (const float*)d_in[6];
  float* out = (float*)d_out;

  u16* hhi = (u16*)d_ws;
  u16* hlo = hhi + H_ELEMS;
  size_t need = (2 * H_ELEMS + WLA_ELEMS + WLB_ELEMS) * sizeof(u16);
  u16 *wlA, *wlB;
  if (ws_size >= need) {
    wlA = hlo + H_ELEMS;
    wlB = wlA + WLA_ELEMS;
  } else {
    wlA = g_wl;
    wlB = g_wl + WLA_ELEMS;
  }

  split_wl<<<256, 512, 0, stream>>>(Wx0, Wxs, Whs, wlA, wlB);

  void* args[] = {&x, &Wx0, &Wxs, &Whs, &bs, &W_head, &b_head,
                  &out, &hhi, &hlo, &wlA, &wlB};
  hipLaunchCooperativeKernel((void*)lstm_persist, dim3(256), dim3(512), args, 0,
                             stream);
}